// Round 6
// baseline (233.589 us; speedup 1.0000x reference)
//
#include <hip/hip_runtime.h>

#define IMG_H 512
#define IMG_W 512
#define VIEW_TAN_F 0.57735026918962576451f  // tan(30 deg)
#define NEARZ 0.1f

#define TILE 16
#define NTX (IMG_W / TILE)      // 32 tiles per row
#define NTILES (NTX * NTX)      // 1024 tiles
#define QCAP 256                // per-round LDS queue capacity (== blockDim)

// Single fused kernel: one block per 16x16 tile. Each block recomputes the
// per-face projection/edge setup for ALL faces (16 rounds x 1 face/thread;
// verts+faces = 72 KB -> L1/L2 resident, redundancy is ~8 us chip-wide),
// ballot-compacts tile survivors into an LDS queue, consumes 1 px/thread
// with an in-register u64 (z_bits<<32|face) lexicographic min (== reference
// strict-< earliest-face tie-break, validated R2-R5). No zbuf / lists /
// global atomics; per-block loss partial written to d_ws.
__global__ __launch_bounds__(256) void raster_fused(
    const float* __restrict__ verts,
    const int* __restrict__ faces,
    const float* __restrict__ tex,
    const float* __restrict__ campos,
    const float* __restrict__ camup,
    const float* __restrict__ imref,
    float* __restrict__ partial,
    int F)
{
    __shared__ float4 sA[QCAP][3];
    __shared__ int    sFi[QCAP];
    __shared__ int    sCnt;

    const int b    = blockIdx.x;
    const int tX   = b & (NTX - 1);
    const int tY   = b >> 5;             // log2(NTX)
    const int tid  = threadIdx.x;
    const int lane = tid & 63;

    // ---- camera basis (uniform; same math as validated prep_faces) ----
    float ex = campos[0], ey = campos[1], ez = campos[2];
    float ux = camup[0], uy = camup[1], uz = camup[2];
    float zxv = -ex, zyv = -ey, zzv = -ez;
    float inv = 1.0f / (sqrtf(zxv*zxv + zyv*zyv + zzv*zzv) + 1e-12f);
    zxv *= inv; zyv *= inv; zzv *= inv;
    inv = 1.0f / (sqrtf(ux*ux + uy*uy + uz*uz) + 1e-12f);
    ux *= inv; uy *= inv; uz *= inv;
    float xxv = uy*zzv - uz*zyv;
    float xyv = uz*zxv - ux*zzv;
    float xzv = ux*zyv - uy*zxv;
    inv = 1.0f / (sqrtf(xxv*xxv + xyv*xyv + xzv*xzv) + 1e-12f);
    xxv *= inv; xyv *= inv; xzv *= inv;
    float yxv = zyv*xzv - zzv*xyv;
    float yyv = zzv*xxv - zxv*xzv;
    float yzv = zxv*xyv - zyv*xxv;

    // ---- tile constants (identical to validated bin_tiles test) ----
    const float cxt = ((float)(tX * TILE + TILE/2)) * (2.0f / IMG_W) - 1.0f;
    const float cyt = 1.0f - ((float)(tY * TILE + TILE/2)) * (2.0f / IMG_H);
    const float hx = (TILE/2) * (2.0f / IMG_W);
    const float hy = (TILE/2) * (2.0f / IMG_H);

    // ---- this thread's pixel ----
    const int colp = tX * TILE + (tid & 15);
    const int rowp = tY * TILE + (tid >> 4);
    const float x = ((float)colp + 0.5f) * (2.0f / IMG_W) - 1.0f;
    const float y = 1.0f - ((float)rowp + 0.5f) * (2.0f / IMG_H);

    unsigned long long best = ~0ull;

    const int rounds = (F + QCAP - 1) / QCAP;
    for (int r = 0; r < rounds; ++r) {
        int f = r * QCAP + tid;
        float4 q0, q1, q2;
        bool pass = false;
        if (f < F) {
            float px_[3], py_[3], pz_[3];
            #pragma unroll
            for (int k = 0; k < 3; ++k) {
                int vi = faces[f*3 + k];
                float vx = verts[vi*3+0] - ex;
                float vy = verts[vi*3+1] - ey;
                float vz = verts[vi*3+2] - ez;
                float cx = xxv*vx + xyv*vy + xzv*vz;
                float cy = yxv*vx + yyv*vy + yzv*vz;
                float cz = zxv*vx + zyv*vy + zzv*vz;
                float denom = cz * VIEW_TAN_F + 1e-12f;
                px_[k] = cx / denom;
                py_[k] = cy / denom;
                pz_[k] = cz;
            }
            float x0 = px_[0], y0 = py_[0];
            float x1 = px_[1], y1 = py_[1];
            float x2 = px_[2], y2 = py_[2];
            float area = (x1-x0)*(y2-y0) - (y1-y0)*(x2-x0);
            bool valid = fabsf(area) > 1e-8f;
            if (valid) {
                float s = (area > 0.0f) ? 1.0f : -1.0f;
                float A0 = -(y2-y1), B0 = (x2-x1), C0 = (y2-y1)*x1 - (x2-x1)*y1;
                float A1 = -(y0-y2), B1 = (x0-x2), C1 = (y0-y2)*x2 - (x0-x2)*y2;
                float A2 = -(y1-y0), B2 = (x1-x0), C2 = (y1-y0)*x0 - (x1-x0)*y0;
                float invs = 1.0f / area;
                float Az = (A0*pz_[0] + A1*pz_[1] + A2*pz_[2]) * invs;
                float Bz = (B0*pz_[0] + B1*pz_[1] + B2*pz_[2]) * invs;
                float Cz = (C0*pz_[0] + C1*pz_[1] + C2*pz_[2]) * invs;
                A0 *= s; B0 *= s; C0 *= s;
                A1 *= s; B1 *= s; C1 *= s;
                A2 *= s; B2 *= s; C2 *= s;
                // conservative dilated-edge test vs tile rect (validated)
                float e0 = fmaf(A0, cxt, fmaf(B0, cyt, C0)) + fabsf(A0)*hx + fabsf(B0)*hy;
                float e1 = fmaf(A1, cxt, fmaf(B1, cyt, C1)) + fabsf(A1)*hx + fabsf(B1)*hy;
                float e2 = fmaf(A2, cxt, fmaf(B2, cyt, C2)) + fabsf(A2)*hx + fabsf(B2)*hy;
                pass = fminf(fminf(e0, e1), e2) >= -1e-6f;
                q0 = make_float4(A0, B0, C0, A1);
                q1 = make_float4(B1, C1, A2, B2);
                q2 = make_float4(C2, Az, Bz, Cz);
            }
        }

        __syncthreads();                 // previous round's queue consumed
        if (tid == 0) sCnt = 0;
        __syncthreads();

        unsigned long long m = __ballot(pass);
        int wbase = 0;
        if (lane == 0 && m) wbase = atomicAdd(&sCnt, __popcll(m));
        wbase = __shfl(wbase, 0, 64);
        if (pass) {
            int pos = wbase + __popcll(m & ((1ull << lane) - 1ull));
            sA[pos][0] = q0;
            sA[pos][1] = q1;
            sA[pos][2] = q2;
            sFi[pos]   = f;
        }
        __syncthreads();
        int n = sCnt;

        for (int s = 0; s < n; ++s) {
            float4 p0 = sA[s][0], p1 = sA[s][1], p2 = sA[s][2];
            int fi = sFi[s];
            float w0 = fmaf(p0.x, x, fmaf(p0.y, y, p0.z));
            float w1 = fmaf(p0.w, x, fmaf(p1.x, y, p1.y));
            float w2 = fmaf(p1.z, x, fmaf(p1.w, y, p2.x));
            float z  = fmaf(p2.y, x, fmaf(p2.z, y, p2.w));
            if ((fminf(fminf(w0, w1), w2) >= 0.0f) && (z > NEARZ)) {
                unsigned long long key =
                    ((unsigned long long)__float_as_uint(z) << 32) | (unsigned)fi;
                if (key < best) best = key;   // lexicographic (z, face) min
            }
        }
    }

    // ---- epilogue: winner color (mean of 8 texels), channel-reversed SSE ----
    float cr = 0.0f, cg = 0.0f, cb = 0.0f;
    if (best != ~0ull) {
        unsigned idx = (unsigned)(best & 0xffffffffull);
        float c0 = 0.0f, c1 = 0.0f, c2 = 0.0f;
        #pragma unroll
        for (int t = 0; t < 8; ++t) {
            c0 += tex[idx*24 + t*3 + 0];
            c1 += tex[idx*24 + t*3 + 1];
            c2 += tex[idx*24 + t*3 + 2];
        }
        cr = c0 * 0.125f; cg = c1 * 0.125f; cb = c2 * 0.125f;
    }
    const int HW = IMG_H * IMG_W;
    const int p = rowp * IMG_W + colp;
    // image[:, ::-1] reverses the CHANNEL axis
    float d0 = cb - imref[0*HW + p];
    float d1 = cg - imref[1*HW + p];
    float d2 = cr - imref[2*HW + p];
    float loss = fmaf(d0, d0, fmaf(d1, d1, d2*d2));

    #pragma unroll
    for (int off = 32; off > 0; off >>= 1)
        loss += __shfl_down(loss, off, 64);

    __shared__ float wsum[4];
    int wid = tid >> 6;
    if (lane == 0) wsum[wid] = loss;
    __syncthreads();
    if (tid == 0)
        partial[b] = wsum[0] + wsum[1] + wsum[2] + wsum[3];
}

// One block: reduce the 1024 per-tile partials into out[0]. No atomics, no
// init-ordering hazard (out written exactly once, after all partials exist).
__global__ __launch_bounds__(256) void finish_loss(
    const float* __restrict__ partial, float* __restrict__ out)
{
    int tid = threadIdx.x;
    float s = partial[tid] + partial[tid + 256]
            + partial[tid + 512] + partial[tid + 768];
    #pragma unroll
    for (int off = 32; off > 0; off >>= 1)
        s += __shfl_down(s, off, 64);
    __shared__ float wsum[4];
    int lane = tid & 63, wid = tid >> 6;
    if (lane == 0) wsum[wid] = s;
    __syncthreads();
    if (tid == 0)
        out[0] = wsum[0] + wsum[1] + wsum[2] + wsum[3];
}

extern "C" void kernel_launch(void* const* d_in, const int* in_sizes, int n_in,
                              void* d_out, int out_size, void* d_ws, size_t ws_size,
                              hipStream_t stream)
{
    const float* verts  = (const float*)d_in[0];
    const int*   faces  = (const int*)d_in[1];
    const float* tex    = (const float*)d_in[2];
    const float* campos = (const float*)d_in[3];
    const float* camup  = (const float*)d_in[4];
    const float* imref  = (const float*)d_in[5];
    int F = in_sizes[1] / 3;

    float* partial = (float*)d_ws;       // NTILES floats
    float* out     = (float*)d_out;

    raster_fused<<<NTILES, 256, 0, stream>>>(verts, faces, tex, campos, camup,
                                             imref, partial, F);
    finish_loss<<<1, 256, 0, stream>>>(partial, out);
}

// Round 7
// 132.357 us; speedup vs baseline: 1.7648x; 1.7648x over previous
//
#include <hip/hip_runtime.h>

#define IMG_H 512
#define IMG_W 512
#define VIEW_TAN_F 0.57735026918962576451f  // tan(30 deg)
#define NEARZ 0.1f

#define T8 8                     // tile side
#define NT8 (IMG_W / T8)         // 64 tiles per row
#define NTILES8 (NT8 * NT8)      // 4096 tiles
#define NWAVES 8                 // waves per block = face splits per tile

// Per-face data: 3 x float4 = {A0,B0,C0,A1},{B1,C1,A2,B2},{C2,Az,Bz,Cz}
// Edge coefficients premultiplied by sign(area): inside <=> w0,w1,w2 >= 0.
// z = Az*x + Bz*y + Cz. Computed ONCE here (R6 lesson: per-block recompute
// with scattered gathers = 3.5 GB L2 traffic death).
__global__ void prep_faces(const float* __restrict__ verts,
                           const int* __restrict__ faces,
                           const float* __restrict__ tex,
                           const float* __restrict__ campos,
                           const float* __restrict__ camup,
                           float4* __restrict__ fd,
                           float* __restrict__ cols,
                           float* __restrict__ out,
                           int F)
{
    int gid = blockIdx.x * blockDim.x + threadIdx.x;
    if (gid == 0 && out) out[0] = 0.0f;     // d_out poisoned 0xAA each call

    int f = gid;
    if (f >= F) return;

    float ex = campos[0], ey = campos[1], ez = campos[2];
    float ux = camup[0], uy = camup[1], uz = camup[2];
    float zxv = -ex, zyv = -ey, zzv = -ez;
    float inv = 1.0f / (sqrtf(zxv*zxv + zyv*zyv + zzv*zzv) + 1e-12f);
    zxv *= inv; zyv *= inv; zzv *= inv;
    inv = 1.0f / (sqrtf(ux*ux + uy*uy + uz*uz) + 1e-12f);
    ux *= inv; uy *= inv; uz *= inv;
    float xxv = uy*zzv - uz*zyv;
    float xyv = uz*zxv - ux*zzv;
    float xzv = ux*zyv - uy*zxv;
    inv = 1.0f / (sqrtf(xxv*xxv + xyv*xyv + xzv*xzv) + 1e-12f);
    xxv *= inv; xyv *= inv; xzv *= inv;
    float yxv = zyv*xzv - zzv*xyv;
    float yyv = zzv*xxv - zxv*xzv;
    float yzv = zxv*xyv - zyv*xxv;

    float px_[3], py_[3], pz_[3];
    #pragma unroll
    for (int k = 0; k < 3; ++k) {
        int vi = faces[f*3 + k];
        float vx = verts[vi*3+0] - ex;
        float vy = verts[vi*3+1] - ey;
        float vz = verts[vi*3+2] - ez;
        float cx = xxv*vx + xyv*vy + xzv*vz;
        float cy = yxv*vx + yyv*vy + yzv*vz;
        float cz = zxv*vx + zyv*vy + zzv*vz;
        float denom = cz * VIEW_TAN_F + 1e-12f;
        px_[k] = cx / denom;
        py_[k] = cy / denom;
        pz_[k] = cz;
    }
    float x0 = px_[0], y0 = py_[0];
    float x1 = px_[1], y1 = py_[1];
    float x2 = px_[2], y2 = py_[2];
    float area = (x1-x0)*(y2-y0) - (y1-y0)*(x2-x0);
    bool valid = fabsf(area) > 1e-8f;
    float safe = valid ? area : 1.0f;
    float s = (area > 0.0f) ? 1.0f : -1.0f;

    float A0 = -(y2-y1), B0 = (x2-x1), C0 = (y2-y1)*x1 - (x2-x1)*y1;
    float A1 = -(y0-y2), B1 = (x0-x2), C1 = (y0-y2)*x2 - (x0-x2)*y2;
    float A2 = -(y1-y0), B2 = (x1-x0), C2 = (y1-y0)*x0 - (x1-x0)*y0;

    float invs = 1.0f / safe;
    float Az = (A0*pz_[0] + A1*pz_[1] + A2*pz_[2]) * invs;
    float Bz = (B0*pz_[0] + B1*pz_[1] + B2*pz_[2]) * invs;
    float Cz = (C0*pz_[0] + C1*pz_[1] + C2*pz_[2]) * invs;

    A0 *= s; B0 *= s; C0 *= s;
    A1 *= s; B1 *= s; C1 *= s;
    A2 *= s; B2 *= s; C2 *= s;

    if (!valid) {
        A0 = B0 = A1 = B1 = A2 = B2 = 0.0f;
        C0 = C1 = C2 = -1.0f;   // always fails inside + tile tests
        Az = Bz = 0.0f; Cz = 0.0f;
    }

    fd[f*3+0] = make_float4(A0, B0, C0, A1);
    fd[f*3+1] = make_float4(B1, C1, A2, B2);
    fd[f*3+2] = make_float4(C2, Az, Bz, Cz);

    float c0 = 0.0f, c1 = 0.0f, c2 = 0.0f;
    #pragma unroll
    for (int t = 0; t < 8; ++t) {
        c0 += tex[f*24 + t*3 + 0];
        c1 += tex[f*24 + t*3 + 1];
        c2 += tex[f*24 + t*3 + 2];
    }
    cols[f*3+0] = c0 * 0.125f;
    cols[f*3+1] = c1 * 0.125f;
    cols[f*3+2] = c2 * 0.125f;
}

// One block per 8x8 pixel tile; 8 waves = 8 face-splits of that tile.
// Wave w streams faces (r*8+w)*64+lane COALESCED from fd, dilated-tests vs
// the 8x8 rect, ballot-compacts into its WAVE-PRIVATE LDS queue, then evals
// its own 64 pixels (1 px/lane) immediately. All main-loop hazards are
// within-wave (DS pipe is in-order per wave); one __syncthreads before the
// cross-wave key-min merge. No zbuf/lists/global intermediates.
__global__ __launch_bounds__(512) void raster_tile8(
    const float4* __restrict__ fd,
    const float* __restrict__ cols,
    const float* __restrict__ imref,
    float* __restrict__ out, int F)
{
    __shared__ float4 sA0[NWAVES][64];
    __shared__ float4 sA1[NWAVES][64];
    __shared__ float4 sA2[NWAVES][64];
    __shared__ int    sFi[NWAVES][64];
    __shared__ unsigned long long sBest[NWAVES * 64];

    const int b    = blockIdx.x;
    const int tX   = b & (NT8 - 1);
    const int tY   = b >> 6;             // log2(NT8)
    const int tid  = threadIdx.x;
    const int w    = tid >> 6;
    const int lane = tid & 63;

    const int colp = tX * T8 + (lane & 7);
    const int rowp = tY * T8 + (lane >> 3);
    const float x = ((float)colp + 0.5f) * (2.0f / IMG_W) - 1.0f;
    const float y = 1.0f - ((float)rowp + 0.5f) * (2.0f / IMG_H);

    const float cxt = ((float)(tX * T8 + T8/2)) * (2.0f / IMG_W) - 1.0f;
    const float cyt = 1.0f - ((float)(tY * T8 + T8/2)) * (2.0f / IMG_H);
    const float hx = (T8/2) * (2.0f / IMG_W);
    const float hy = (T8/2) * (2.0f / IMG_H);

    unsigned long long best = ~0ull;

    const int rounds = (F + NWAVES*64 - 1) / (NWAVES*64);
    for (int r = 0; r < rounds; ++r) {
        int f = (r * NWAVES + w) * 64 + lane;
        bool pass = false;
        float4 q0, q1, q2;
        if (f < F) {
            q0 = fd[3*f + 0];
            q1 = fd[3*f + 1];
            q2 = fd[3*f + 2];
            float e0 = fmaf(q0.x, cxt, fmaf(q0.y, cyt, q0.z)) + fabsf(q0.x)*hx + fabsf(q0.y)*hy;
            float e1 = fmaf(q0.w, cxt, fmaf(q1.x, cyt, q1.y)) + fabsf(q0.w)*hx + fabsf(q1.x)*hy;
            float e2 = fmaf(q1.z, cxt, fmaf(q1.w, cyt, q2.x)) + fabsf(q1.z)*hx + fabsf(q1.w)*hy;
            pass = fminf(fminf(e0, e1), e2) >= -1e-6f;
        }

        unsigned long long m = __ballot(pass);
        int cnt = __popcll(m);           // wave-uniform
        if (pass) {
            int pos = __popcll(m & ((1ull << lane) - 1ull));
            sA0[w][pos] = q0;
            sA1[w][pos] = q1;
            sA2[w][pos] = q2;
            sFi[w][pos] = f;
        }
        __builtin_amdgcn_wave_barrier();  // pin produce->consume scheduling

        for (int s = 0; s < cnt; ++s) {
            float4 p0 = sA0[w][s], p1 = sA1[w][s], p2 = sA2[w][s];
            int fi = sFi[w][s];
            float w0 = fmaf(p0.x, x, fmaf(p0.y, y, p0.z));
            float w1 = fmaf(p0.w, x, fmaf(p1.x, y, p1.y));
            float w2 = fmaf(p1.z, x, fmaf(p1.w, y, p2.x));
            float z  = fmaf(p2.y, x, fmaf(p2.z, y, p2.w));
            if ((fminf(fminf(w0, w1), w2) >= 0.0f) && (z > NEARZ)) {
                unsigned long long key =
                    ((unsigned long long)__float_as_uint(z) << 32) | (unsigned)fi;
                if (key < best) best = key;   // lexicographic (z, face) min
            }
        }
        __builtin_amdgcn_wave_barrier();  // pin consume->next-produce
    }

    sBest[tid] = best;
    __syncthreads();

    if (w == 0) {
        unsigned long long mk = sBest[lane];
        #pragma unroll
        for (int ww = 1; ww < NWAVES; ++ww) {
            unsigned long long o = sBest[ww*64 + lane];
            if (o < mk) mk = o;
        }
        float cr = 0.0f, cg = 0.0f, cb = 0.0f;
        if (mk != ~0ull) {
            unsigned idx = (unsigned)(mk & 0xffffffffull);
            cr = cols[idx*3 + 0];
            cg = cols[idx*3 + 1];
            cb = cols[idx*3 + 2];
        }
        const int HW = IMG_H * IMG_W;
        const int p = rowp * IMG_W + colp;
        // image[:, ::-1] reverses the CHANNEL axis
        float d0 = cb - imref[0*HW + p];
        float d1 = cg - imref[1*HW + p];
        float d2 = cr - imref[2*HW + p];
        float loss = fmaf(d0, d0, fmaf(d1, d1, d2*d2));
        #pragma unroll
        for (int off = 32; off > 0; off >>= 1)
            loss += __shfl_down(loss, off, 64);
        if (lane == 0)
            atomicAdd(out, loss);        // out zeroed by prep_faces (ordered)
    }
}

// Fallback (small ws): Round-1 monolithic kernel (validated absmax 0).
__global__ __launch_bounds__(256) void raster_loss_mono(
    const float4* __restrict__ fd,
    const float* __restrict__ cols,
    const float* __restrict__ imref,
    float* __restrict__ out, int F)
{
    int p = blockIdx.x * 256 + threadIdx.x;
    int col = p & (IMG_W - 1);
    float x = ((float)col + 0.5f) * (2.0f / IMG_W) - 1.0f;
    float y = 1.0f - ((float)(p >> 9) + 0.5f) * (2.0f / IMG_H);

    float bestz = 1e10f;
    int besti = -1;
    for (int f = 0; f < F; ++f) {
        float4 q0 = fd[3*f + 0];
        float4 q1 = fd[3*f + 1];
        float4 q2 = fd[3*f + 2];
        float w0 = fmaf(q0.x, x, fmaf(q0.y, y, q0.z));
        float w1 = fmaf(q0.w, x, fmaf(q1.x, y, q1.y));
        float w2 = fmaf(q1.z, x, fmaf(q1.w, y, q2.x));
        float z  = fmaf(q2.y, x, fmaf(q2.z, y, q2.w));
        bool hit = (w0 >= 0.0f) & (w1 >= 0.0f) & (w2 >= 0.0f) & (z > NEARZ);
        float zm = hit ? z : 1e10f;
        if (zm < bestz) { bestz = zm; besti = f; }
    }
    float r = 0.0f, g = 0.0f, bl = 0.0f;
    if (besti >= 0) { r = cols[besti*3]; g = cols[besti*3+1]; bl = cols[besti*3+2]; }
    const int HW = IMG_H * IMG_W;
    float d0 = bl - imref[p], d1 = g - imref[HW+p], d2 = r - imref[2*HW+p];
    float loss = fmaf(d0, d0, fmaf(d1, d1, d2*d2));
    #pragma unroll
    for (int off = 32; off > 0; off >>= 1)
        loss += __shfl_down(loss, off, 64);
    __shared__ float wsum[4];
    int wid = threadIdx.x >> 6, lane = threadIdx.x & 63;
    if (lane == 0) wsum[wid] = loss;
    __syncthreads();
    if (threadIdx.x == 0)
        atomicAdd(out, wsum[0] + wsum[1] + wsum[2] + wsum[3]);
}

extern "C" void kernel_launch(void* const* d_in, const int* in_sizes, int n_in,
                              void* d_out, int out_size, void* d_ws, size_t ws_size,
                              hipStream_t stream)
{
    const float* verts  = (const float*)d_in[0];
    const int*   faces  = (const int*)d_in[1];
    const float* tex    = (const float*)d_in[2];
    const float* campos = (const float*)d_in[3];
    const float* camup  = (const float*)d_in[4];
    const float* imref  = (const float*)d_in[5];
    int F = in_sizes[1] / 3;

    size_t fdbytes = (size_t)F * 3 * sizeof(float4);
    size_t cbytes  = (size_t)F * 3 * sizeof(float);
    float* out = (float*)d_out;

    float4* fd   = (float4*)d_ws;
    float*  cols = (float*)((char*)d_ws + fdbytes);

    if (ws_size >= fdbytes + cbytes) {
        prep_faces<<<(F + 255)/256, 256, 0, stream>>>(verts, faces, tex, campos, camup,
                                                      fd, cols, out, F);
        raster_tile8<<<NTILES8, 512, 0, stream>>>(fd, cols, imref, out, F);
    } else {
        hipMemsetAsync(d_out, 0, sizeof(float), stream);
        prep_faces<<<(F + 255)/256, 256, 0, stream>>>(verts, faces, tex, campos, camup,
                                                      fd, cols, (float*)nullptr, F);
        raster_loss_mono<<<(IMG_H*IMG_W)/256, 256, 0, stream>>>(fd, cols, imref, out, F);
    }
}